// Round 1
// baseline (219.512 us; speedup 1.0000x reference)
//
#include <hip/hip_runtime.h>

// ResamplerLayer: trilinear resample, ZERO-boundary (replicate-clamp) semantics.
// inputs:  d_in[0] = inputs        [B=2,128,128,128,C=4] f32
//          d_in[1] = sample_coords [B=2,96,96,96,3]      f32  (order: D,H,W)
// output:  d_out   = [B=2,96,96,96,4] f32

constexpr int D = 128, H = 128, W = 128;
constexpr int OD = 96, OH = 96, OW = 96;
constexpr int VOX_PER_B = OD * OH * OW;          // 884736
constexpr int NVOX = 2 * VOX_PER_B;              // 1769472 (B=2)

__device__ __forceinline__ float4 f4_fma(float w, float4 a, float4 acc) {
    acc.x = fmaf(w, a.x, acc.x);
    acc.y = fmaf(w, a.y, acc.y);
    acc.z = fmaf(w, a.z, acc.z);
    acc.w = fmaf(w, a.w, acc.w);
    return acc;
}
__device__ __forceinline__ float4 f4_scale(float w, float4 a) {
    return make_float4(w * a.x, w * a.y, w * a.z, w * a.w);
}

__global__ __launch_bounds__(256) void resampler_kernel(
    const float* __restrict__ inp,
    const float* __restrict__ coords,
    float4* __restrict__ out)
{
    int idx = blockIdx.x * blockDim.x + threadIdx.x;
    if (idx >= NVOX) return;

    // coords layout [..., 3]: dim0=D(z), dim1=H(y), dim2=W(x)
    const float cz = coords[idx * 3 + 0];
    const float cy = coords[idx * 3 + 1];
    const float cx = coords[idx * 3 + 2];
    const int b = (idx >= VOX_PER_B) ? 1 : 0;

    const int fz = (int)floorf(cz);
    const int fy = (int)floorf(cy);
    const int fx = (int)floorf(cx);

    // ceil_i = clip(floor+1, 0, S-1) from UNCLAMPED floor; then clamp floor.
    const int z1 = min(max(fz + 1, 0), D - 1);
    const int y1 = min(max(fy + 1, 0), H - 1);
    const int x1 = min(max(fx + 1, 0), W - 1);
    const int z0 = min(max(fz, 0), D - 1);
    const int y0 = min(max(fy, 0), H - 1);
    const int x0 = min(max(fx, 0), W - 1);

    // floor-corner weight = w_1 = ceil_i - c ; ceil-corner weight = w_0 = c - floor_i
    const float wz0 = (float)z1 - cz, wz1 = cz - (float)z0;
    const float wy0 = (float)y1 - cy, wy1 = cy - (float)y0;
    const float wx0 = (float)x1 - cx, wx1 = cx - (float)x0;

    // input as float4 (C=4 contiguous): index (z<<14)|(y<<7)|x within batch
    const float4* bp = (const float4*)inp + ((size_t)b << 21);  // D*H*W = 2^21

    const int z0o = z0 << 14, z1o = z1 << 14;
    const int y0o = y0 << 7,  y1o = y1 << 7;

    const float4 s000 = bp[z0o | y0o | x0];
    const float4 s001 = bp[z0o | y0o | x1];
    const float4 s010 = bp[z0o | y1o | x0];
    const float4 s011 = bp[z0o | y1o | x1];
    const float4 s100 = bp[z1o | y0o | x0];
    const float4 s101 = bp[z1o | y0o | x1];
    const float4 s110 = bp[z1o | y1o | x0];
    const float4 s111 = bp[z1o | y1o | x1];

    // blend along x, then y, then z (exact factorization of the 8-corner sum)
    float4 c00 = f4_fma(wx1, s001, f4_scale(wx0, s000));
    float4 c01 = f4_fma(wx1, s011, f4_scale(wx0, s010));
    float4 c10 = f4_fma(wx1, s101, f4_scale(wx0, s100));
    float4 c11 = f4_fma(wx1, s111, f4_scale(wx0, s110));

    float4 c0 = f4_fma(wy1, c01, f4_scale(wy0, c00));
    float4 c1 = f4_fma(wy1, c11, f4_scale(wy0, c10));

    out[idx] = f4_fma(wz1, c1, f4_scale(wz0, c0));
}

extern "C" void kernel_launch(void* const* d_in, const int* in_sizes, int n_in,
                              void* d_out, int out_size, void* d_ws, size_t ws_size,
                              hipStream_t stream) {
    const float* inp    = (const float*)d_in[0];
    const float* coords = (const float*)d_in[1];
    float4* out = (float4*)d_out;

    const int threads = 256;
    const int blocks = (NVOX + threads - 1) / threads;  // 6912
    resampler_kernel<<<blocks, threads, 0, stream>>>(inp, coords, out);
}